// Round 6
// baseline (747.855 us; speedup 1.0000x reference)
//
#include <hip/hip_runtime.h>
#include <math.h>

#define IN_NF 16
#define IN_EF 8
#define OUT_NF 16
#define H1 8
#define H2 8
#define H_IN 16
#define D_IN 40   // 2*IN_NF + IN_EF
#define NT 4      // threads cooperating per node (gather)
#define SCAN_NB 128  // scan blocks per array
#define EDGE_BLOCKS 1280

// ---------------------------------------------------------------------------
// bf16 helpers (RNE)
// ---------------------------------------------------------------------------
__device__ __forceinline__ unsigned int f2bf_bits(float f) {
    unsigned int u = __float_as_uint(f);
    u += 0x7FFFu + ((u >> 16) & 1u);
    return u >> 16;
}
__device__ __forceinline__ float bf_lo(unsigned int w) { return __uint_as_float(w << 16); }
__device__ __forceinline__ float bf_hi(unsigned int w) { return __uint_as_float(w & 0xFFFF0000u); }

// ---------------------------------------------------------------------------
// Fused prepass: blocks [0, nb_conv) convert nf -> bf16; rest do the
// destination histogram for both graphs (int atomics, int4 loads).
// ---------------------------------------------------------------------------
__global__ __launch_bounds__(256) void k_pre(
    const float* __restrict__ nf, unsigned short* __restrict__ nf16, int n_nodes,
    const int* __restrict__ dst_out, const int* __restrict__ dst_in,
    int* __restrict__ curA, int* __restrict__ curB, int n_edges, int nb_conv)
{
    if ((int)blockIdx.x < nb_conv) {
        int n = blockIdx.x * 256 + threadIdx.x;
        if (n >= n_nodes) return;
        const float4* p = (const float4*)(nf + (long)n * IN_NF);
        unsigned int w[8];
#pragma unroll
        for (int q = 0; q < 4; ++q) {
            float4 v = p[q];
            w[2*q+0] = f2bf_bits(v.x) | (f2bf_bits(v.y) << 16);
            w[2*q+1] = f2bf_bits(v.z) | (f2bf_bits(v.w) << 16);
        }
        uint4* o = (uint4*)(nf16 + (size_t)n * 16);
        o[0] = make_uint4(w[0], w[1], w[2], w[3]);
        o[1] = make_uint4(w[4], w[5], w[6], w[7]);
    } else {
        int i = ((blockIdx.x - nb_conv) * 256 + threadIdx.x) * 4;
        if (i + 3 < n_edges) {
            int4 a = *(const int4*)(dst_out + i);
            atomicAdd(&curA[a.x], 1); atomicAdd(&curA[a.y], 1);
            atomicAdd(&curA[a.z], 1); atomicAdd(&curA[a.w], 1);
            int4 b = *(const int4*)(dst_in + i);
            atomicAdd(&curB[b.x], 1); atomicAdd(&curB[b.y], 1);
            atomicAdd(&curB[b.z], 1); atomicAdd(&curB[b.w], 1);
        } else {
            for (int e = i; e < n_edges; ++e) {
                atomicAdd(&curA[dst_out[e]], 1);
                atomicAdd(&curB[dst_in[e]], 1);
            }
        }
    }
}

// standalone hist for the fallback path
__global__ __launch_bounds__(256) void k_hist(
    const int* __restrict__ dst_out, const int* __restrict__ dst_in,
    int* __restrict__ off_out, int* __restrict__ off_in, int n_edges)
{
    int i = (blockIdx.x * blockDim.x + threadIdx.x) * 4;
    if (i + 3 < n_edges) {
        int4 a = *(const int4*)(dst_out + i);
        atomicAdd(&off_out[a.x], 1); atomicAdd(&off_out[a.y], 1);
        atomicAdd(&off_out[a.z], 1); atomicAdd(&off_out[a.w], 1);
        int4 b = *(const int4*)(dst_in + i);
        atomicAdd(&off_in[b.x], 1); atomicAdd(&off_in[b.y], 1);
        atomicAdd(&off_in[b.z], 1); atomicAdd(&off_in[b.w], 1);
    } else {
        for (int e = i; e < n_edges; ++e) {
            atomicAdd(&off_out[dst_out[e]], 1);
            atomicAdd(&off_in[dst_in[e]], 1);
        }
    }
}

// ---------------------------------------------------------------------------
// Hierarchical exclusive scan over two adjacent arrays a0,a1 (n each).
// ---------------------------------------------------------------------------
__global__ __launch_bounds__(256) void k_scan_partial(
    const int* __restrict__ a0, const int* __restrict__ a1, int n,
    int* __restrict__ bsum)
{
    int arr = blockIdx.x >> 7;           // /SCAN_NB
    int blk = blockIdx.x & (SCAN_NB - 1);
    const int* a = arr ? a1 : a0;
    int chunk = (n + SCAN_NB - 1) / SCAN_NB;
    int beg = blk * chunk;
    int end = min(beg + chunk, n);
    int s = 0;
    for (int i = beg + threadIdx.x; i < end; i += 256) s += a[i];
    __shared__ int sm[256];
    int t = threadIdx.x;
    sm[t] = s;
    __syncthreads();
    for (int d = 128; d > 0; d >>= 1) {
        if (t < d) sm[t] += sm[t + d];
        __syncthreads();
    }
    if (t == 0) bsum[arr * SCAN_NB + blk] = sm[0];
}

__global__ __launch_bounds__(64) void k_scan_bsum(int* __restrict__ bsum)
{
    int arr = threadIdx.x;
    if (arr >= 2) return;
    int run = 0;
    for (int i = 0; i < SCAN_NB; ++i) {
        int v = bsum[arr * SCAN_NB + i];
        bsum[arr * SCAN_NB + i] = run;
        run += v;
    }
}

__global__ __launch_bounds__(256) void k_scan_final(
    int* __restrict__ a0, int* __restrict__ a1, int n,
    const int* __restrict__ bsum)
{
    int arr = blockIdx.x >> 7;
    int blk = blockIdx.x & (SCAN_NB - 1);
    int* a = arr ? a1 : a0;
    int chunk = (n + SCAN_NB - 1) / SCAN_NB;
    int beg = blk * chunk;
    int end = min(beg + chunk, n);
    int t = threadIdx.x;
    __shared__ int sm[256];
    __shared__ int carry_sm;
    if (t == 0) carry_sm = bsum[arr * SCAN_NB + blk];
    __syncthreads();
    for (int base = beg; base < end; base += 256) {
        int i = base + t;
        int v = (i < end) ? a[i] : 0;
        sm[t] = v;
        __syncthreads();
        for (int d = 1; d < 256; d <<= 1) {
            int u = (t >= d) ? sm[t - d] : 0;
            __syncthreads();
            sm[t] += u;
            __syncthreads();
        }
        int carry = carry_sm;
        if (i < end) a[i] = carry + sm[t] - v;   // exclusive
        __syncthreads();
        if (t == 0) carry_sm = carry + sm[255];
        __syncthreads();
    }
}

// ---------------------------------------------------------------------------
// Edge kernel A (MLP_msg_o2i): grid-stride persistent threads, 2 edges per
// iteration (strided by T for coalescing), software-pipelined: all vector
// loads + slot atomics + next-index prefetch issued before the MLPs. Staging
// kept packed (bf16 words / float4) so both MLPs run sequentially on shared
// h/o registers — no spills at 128 VGPR.
// ---------------------------------------------------------------------------
__global__ __launch_bounds__(256, 4) void k_edge_a(
    const unsigned short* __restrict__ nf16,
    const int* __restrict__ src, const int* __restrict__ dst,
    const float* __restrict__ nef,
    const float* __restrict__ W1, const float* __restrict__ B1,
    const float* __restrict__ W2, const float* __restrict__ B2,
    int* __restrict__ cursor, unsigned short* __restrict__ msg,
    int n_edges, int T)
{
    int tid = blockIdx.x * blockDim.x + threadIdx.x;
    int T2 = T * 2;

    int e0 = tid, e1 = tid + T;
    bool p0 = e0 < n_edges;
    bool p1 = e1 < n_edges;
    int s0 = 0, d0 = 0, s1 = 0, d1 = 0;
    if (p0) { s0 = src[e0]; d0 = dst[e0]; }
    if (p1) { s1 = src[e1]; d1 = dst[e1]; }

    while (p0) {
        // ---- issue vector loads for the current pair
        const uint4* pS0 = (const uint4*)(nf16 + (size_t)s0 * 16);
        uint4 Sa = pS0[0], Sb = pS0[1];
        const uint4* pD0 = (const uint4*)(nf16 + (size_t)d0 * 16);
        uint4 Da = pD0[0], Db = pD0[1];
        const float4* pN0 = (const float4*)(nef + (size_t)e0 * IN_EF);
        float4 Na = pN0[0], Nb = pN0[1];
        uint4 Sc, Sd, Dc, Dd; float4 Nc, Nd;
        if (p1) {
            const uint4* pS1 = (const uint4*)(nf16 + (size_t)s1 * 16);
            Sc = pS1[0]; Sd = pS1[1];
            const uint4* pD1 = (const uint4*)(nf16 + (size_t)d1 * 16);
            Dc = pD1[0]; Dd = pD1[1];
            const float4* pN1 = (const float4*)(nef + (size_t)e1 * IN_EF);
            Nc = pN1[0]; Nd = pN1[1];
        }
        // ---- slot atomics (results needed only at store time)
        int slot0 = atomicAdd(&cursor[d0], 1);
        int slot1 = p1 ? atomicAdd(&cursor[d1], 1) : 0;
        // ---- prefetch next-iteration indices
        int f0 = e0 + T2, f1 = e1 + T2;
        bool q0 = f0 < n_edges, q1 = f1 < n_edges;
        int ts0 = 0, td0 = 0, ts1 = 0, td1 = 0;
        if (q0) { ts0 = src[f0]; td0 = dst[f0]; }
        if (q1) { ts1 = src[f1]; td1 = dst[f1]; }

        // ================= MLP edge0 =================
        {
            float h[H_IN];
#pragma unroll
            for (int j = 0; j < H_IN; ++j) h[j] = B1[j];
            unsigned int wS[8] = {Sa.x,Sa.y,Sa.z,Sa.w,Sb.x,Sb.y,Sb.z,Sb.w};
            unsigned int wD[8] = {Da.x,Da.y,Da.z,Da.w,Db.x,Db.y,Db.z,Db.w};
#pragma unroll
            for (int w = 0; w < 8; ++w) {
                float a0 = bf_lo(wS[w]), a1 = bf_hi(wS[w]);
                float b0 = bf_lo(wD[w]), b1 = bf_hi(wD[w]);
                const float* r0 = W1 + (2*w) * H_IN;
                const float* r1 = W1 + (2*w+1) * H_IN;
                const float* r2 = W1 + (IN_NF + 2*w) * H_IN;
                const float* r3 = W1 + (IN_NF + 2*w+1) * H_IN;
#pragma unroll
                for (int j = 0; j < H_IN; ++j) {
                    h[j] = fmaf(a0, r0[j], h[j]);
                    h[j] = fmaf(a1, r1[j], h[j]);
                    h[j] = fmaf(b0, r2[j], h[j]);
                    h[j] = fmaf(b1, r3[j], h[j]);
                }
            }
            float nv[8] = {Na.x,Na.y,Na.z,Na.w,Nb.x,Nb.y,Nb.z,Nb.w};
#pragma unroll
            for (int k = 0; k < IN_EF; ++k) {
                const float* r = W1 + (2*IN_NF + k) * H_IN;
                float a0 = nv[k];
#pragma unroll
                for (int j = 0; j < H_IN; ++j) h[j] = fmaf(a0, r[j], h[j]);
            }
#pragma unroll
            for (int j = 0; j < H_IN; ++j) h[j] = (h[j] >= 0.f) ? h[j] : 0.2f * h[j];

            float o[OUT_NF];
#pragma unroll
            for (int j = 0; j < OUT_NF; ++j) o[j] = B2[j];
#pragma unroll
            for (int k = 0; k < H_IN; ++k) {
                float hk = h[k];
                const float* r = W2 + k * OUT_NF;
#pragma unroll
                for (int j = 0; j < OUT_NF; ++j) o[j] = fmaf(hk, r[j], o[j]);
            }
            unsigned int w[8];
#pragma unroll
            for (int q = 0; q < 8; ++q)
                w[q] = f2bf_bits(o[2*q]) | (f2bf_bits(o[2*q+1]) << 16);
            uint4* pm = (uint4*)(msg + (size_t)slot0 * 16);
            pm[0] = make_uint4(w[0], w[1], w[2], w[3]);
            pm[1] = make_uint4(w[4], w[5], w[6], w[7]);
        }

        // ================= MLP edge1 =================
        if (p1) {
            float h[H_IN];
#pragma unroll
            for (int j = 0; j < H_IN; ++j) h[j] = B1[j];
            unsigned int wS[8] = {Sc.x,Sc.y,Sc.z,Sc.w,Sd.x,Sd.y,Sd.z,Sd.w};
            unsigned int wD[8] = {Dc.x,Dc.y,Dc.z,Dc.w,Dd.x,Dd.y,Dd.z,Dd.w};
#pragma unroll
            for (int w = 0; w < 8; ++w) {
                float a0 = bf_lo(wS[w]), a1 = bf_hi(wS[w]);
                float b0 = bf_lo(wD[w]), b1 = bf_hi(wD[w]);
                const float* r0 = W1 + (2*w) * H_IN;
                const float* r1 = W1 + (2*w+1) * H_IN;
                const float* r2 = W1 + (IN_NF + 2*w) * H_IN;
                const float* r3 = W1 + (IN_NF + 2*w+1) * H_IN;
#pragma unroll
                for (int j = 0; j < H_IN; ++j) {
                    h[j] = fmaf(a0, r0[j], h[j]);
                    h[j] = fmaf(a1, r1[j], h[j]);
                    h[j] = fmaf(b0, r2[j], h[j]);
                    h[j] = fmaf(b1, r3[j], h[j]);
                }
            }
            float nv[8] = {Nc.x,Nc.y,Nc.z,Nc.w,Nd.x,Nd.y,Nd.z,Nd.w};
#pragma unroll
            for (int k = 0; k < IN_EF; ++k) {
                const float* r = W1 + (2*IN_NF + k) * H_IN;
                float a0 = nv[k];
#pragma unroll
                for (int j = 0; j < H_IN; ++j) h[j] = fmaf(a0, r[j], h[j]);
            }
#pragma unroll
            for (int j = 0; j < H_IN; ++j) h[j] = (h[j] >= 0.f) ? h[j] : 0.2f * h[j];

            float o[OUT_NF];
#pragma unroll
            for (int j = 0; j < OUT_NF; ++j) o[j] = B2[j];
#pragma unroll
            for (int k = 0; k < H_IN; ++k) {
                float hk = h[k];
                const float* r = W2 + k * OUT_NF;
#pragma unroll
                for (int j = 0; j < OUT_NF; ++j) o[j] = fmaf(hk, r[j], o[j]);
            }
            unsigned int w[8];
#pragma unroll
            for (int q = 0; q < 8; ++q)
                w[q] = f2bf_bits(o[2*q]) | (f2bf_bits(o[2*q+1]) << 16);
            uint4* pm = (uint4*)(msg + (size_t)slot1 * 16);
            pm[0] = make_uint4(w[0], w[1], w[2], w[3]);
            pm[1] = make_uint4(w[4], w[5], w[6], w[7]);
        }

        e0 = f0; e1 = f1;
        s0 = ts0; d0 = td0; s1 = ts1; d1 = td1;
        p0 = q0; p1 = q1;
    }
}

// ---------------------------------------------------------------------------
// Edge kernel B (MLP_msg_i2o, gated): same pipelined structure, M=17 + gate.
// ---------------------------------------------------------------------------
__global__ __launch_bounds__(256, 4) void k_edge_b(
    const unsigned short* __restrict__ nf16,
    const int* __restrict__ src, const int* __restrict__ dst,
    const float* __restrict__ nef,
    const float* __restrict__ W1, const float* __restrict__ B1,
    const float* __restrict__ W2, const float* __restrict__ B2,
    int* __restrict__ cursor, unsigned short* __restrict__ msg,
    int n_edges, int T)
{
    int tid = blockIdx.x * blockDim.x + threadIdx.x;
    int T2 = T * 2;
    const int M = 1 + H1 + H2; // 17

    int e0 = tid, e1 = tid + T;
    bool p0 = e0 < n_edges;
    bool p1 = e1 < n_edges;
    int s0 = 0, d0 = 0, s1 = 0, d1 = 0;
    if (p0) { s0 = src[e0]; d0 = dst[e0]; }
    if (p1) { s1 = src[e1]; d1 = dst[e1]; }

    while (p0) {
        const uint4* pS0 = (const uint4*)(nf16 + (size_t)s0 * 16);
        uint4 Sa = pS0[0], Sb = pS0[1];
        const uint4* pD0 = (const uint4*)(nf16 + (size_t)d0 * 16);
        uint4 Da = pD0[0], Db = pD0[1];
        const float4* pN0 = (const float4*)(nef + (size_t)e0 * IN_EF);
        float4 Na = pN0[0], Nb = pN0[1];
        uint4 Sc, Sd, Dc, Dd; float4 Nc, Nd;
        if (p1) {
            const uint4* pS1 = (const uint4*)(nf16 + (size_t)s1 * 16);
            Sc = pS1[0]; Sd = pS1[1];
            const uint4* pD1 = (const uint4*)(nf16 + (size_t)d1 * 16);
            Dc = pD1[0]; Dd = pD1[1];
            const float4* pN1 = (const float4*)(nef + (size_t)e1 * IN_EF);
            Nc = pN1[0]; Nd = pN1[1];
        }
        int slot0 = atomicAdd(&cursor[d0], 1);
        int slot1 = p1 ? atomicAdd(&cursor[d1], 1) : 0;
        int f0 = e0 + T2, f1 = e1 + T2;
        bool q0 = f0 < n_edges, q1 = f1 < n_edges;
        int ts0 = 0, td0 = 0, ts1 = 0, td1 = 0;
        if (q0) { ts0 = src[f0]; td0 = dst[f0]; }
        if (q1) { ts1 = src[f1]; td1 = dst[f1]; }

        // ================= MLP edge0 =================
        {
            float h[H_IN];
#pragma unroll
            for (int j = 0; j < H_IN; ++j) h[j] = B1[j];
            unsigned int wS[8] = {Sa.x,Sa.y,Sa.z,Sa.w,Sb.x,Sb.y,Sb.z,Sb.w};
            unsigned int wD[8] = {Da.x,Da.y,Da.z,Da.w,Db.x,Db.y,Db.z,Db.w};
#pragma unroll
            for (int w = 0; w < 8; ++w) {
                float a0 = bf_lo(wS[w]), a1 = bf_hi(wS[w]);
                float b0 = bf_lo(wD[w]), b1 = bf_hi(wD[w]);
                const float* r0 = W1 + (2*w) * H_IN;
                const float* r1 = W1 + (2*w+1) * H_IN;
                const float* r2 = W1 + (IN_NF + 2*w) * H_IN;
                const float* r3 = W1 + (IN_NF + 2*w+1) * H_IN;
#pragma unroll
                for (int j = 0; j < H_IN; ++j) {
                    h[j] = fmaf(a0, r0[j], h[j]);
                    h[j] = fmaf(a1, r1[j], h[j]);
                    h[j] = fmaf(b0, r2[j], h[j]);
                    h[j] = fmaf(b1, r3[j], h[j]);
                }
            }
            float nv[8] = {Na.x,Na.y,Na.z,Na.w,Nb.x,Nb.y,Nb.z,Nb.w};
#pragma unroll
            for (int k = 0; k < IN_EF; ++k) {
                const float* r = W1 + (2*IN_NF + k) * H_IN;
                float a0 = nv[k];
#pragma unroll
                for (int j = 0; j < H_IN; ++j) h[j] = fmaf(a0, r[j], h[j]);
            }
#pragma unroll
            for (int j = 0; j < H_IN; ++j) h[j] = (h[j] >= 0.f) ? h[j] : 0.2f * h[j];

            float o[17];
#pragma unroll
            for (int j = 0; j < M; ++j) o[j] = B2[j];
#pragma unroll
            for (int k = 0; k < H_IN; ++k) {
                float hk = h[k];
                const float* r = W2 + k * M;
#pragma unroll
                for (int j = 0; j < M; ++j) o[j] = fmaf(hk, r[j], o[j]);
            }
            float g = 1.f / (1.f + __expf(-o[0]));
            unsigned int w[8];
#pragma unroll
            for (int q = 0; q < 8; ++q)
                w[q] = f2bf_bits(o[1+2*q] * g) | (f2bf_bits(o[2+2*q] * g) << 16);
            uint4* pm = (uint4*)(msg + (size_t)slot0 * 16);
            pm[0] = make_uint4(w[0], w[1], w[2], w[3]);
            pm[1] = make_uint4(w[4], w[5], w[6], w[7]);
        }

        // ================= MLP edge1 =================
        if (p1) {
            float h[H_IN];
#pragma unroll
            for (int j = 0; j < H_IN; ++j) h[j] = B1[j];
            unsigned int wS[8] = {Sc.x,Sc.y,Sc.z,Sc.w,Sd.x,Sd.y,Sd.z,Sd.w};
            unsigned int wD[8] = {Dc.x,Dc.y,Dc.z,Dc.w,Dd.x,Dd.y,Dd.z,Dd.w};
#pragma unroll
            for (int w = 0; w < 8; ++w) {
                float a0 = bf_lo(wS[w]), a1 = bf_hi(wS[w]);
                float b0 = bf_lo(wD[w]), b1 = bf_hi(wD[w]);
                const float* r0 = W1 + (2*w) * H_IN;
                const float* r1 = W1 + (2*w+1) * H_IN;
                const float* r2 = W1 + (IN_NF + 2*w) * H_IN;
                const float* r3 = W1 + (IN_NF + 2*w+1) * H_IN;
#pragma unroll
                for (int j = 0; j < H_IN; ++j) {
                    h[j] = fmaf(a0, r0[j], h[j]);
                    h[j] = fmaf(a1, r1[j], h[j]);
                    h[j] = fmaf(b0, r2[j], h[j]);
                    h[j] = fmaf(b1, r3[j], h[j]);
                }
            }
            float nv[8] = {Nc.x,Nc.y,Nc.z,Nc.w,Nd.x,Nd.y,Nd.z,Nd.w};
#pragma unroll
            for (int k = 0; k < IN_EF; ++k) {
                const float* r = W1 + (2*IN_NF + k) * H_IN;
                float a0 = nv[k];
#pragma unroll
                for (int j = 0; j < H_IN; ++j) h[j] = fmaf(a0, r[j], h[j]);
            }
#pragma unroll
            for (int j = 0; j < H_IN; ++j) h[j] = (h[j] >= 0.f) ? h[j] : 0.2f * h[j];

            float o[17];
#pragma unroll
            for (int j = 0; j < M; ++j) o[j] = B2[j];
#pragma unroll
            for (int k = 0; k < H_IN; ++k) {
                float hk = h[k];
                const float* r = W2 + k * M;
#pragma unroll
                for (int j = 0; j < M; ++j) o[j] = fmaf(hk, r[j], o[j]);
            }
            float g = 1.f / (1.f + __expf(-o[0]));
            unsigned int w[8];
#pragma unroll
            for (int q = 0; q < 8; ++q)
                w[q] = f2bf_bits(o[1+2*q] * g) | (f2bf_bits(o[2+2*q] * g) << 16);
            uint4* pm = (uint4*)(msg + (size_t)slot1 * 16);
            pm[0] = make_uint4(w[0], w[1], w[2], w[3]);
            pm[1] = make_uint4(w[4], w[5], w[6], w[7]);
        }

        e0 = f0; e1 = f1;
        s0 = ts0; d0 = td0; s1 = ts1; d1 = td1;
        p0 = q0; p1 = q1;
    }
}

// ---------------------------------------------------------------------------
// Gather: NT lanes/node stream contiguous bf16 messages, reduce, reduce-MLP.
// ---------------------------------------------------------------------------
__global__ __launch_bounds__(256, 4) void k_gather(
    const int* __restrict__ curA, const int* __restrict__ curB,
    const unsigned short* __restrict__ msgA, const unsigned short* __restrict__ msgB,
    const float* __restrict__ w_red1, const float* __restrict__ b_red1,
    const float* __restrict__ w_red2, const float* __restrict__ b_red2,
    float* __restrict__ out, int n_nodes)
{
    int tid = blockIdx.x * blockDim.x + threadIdx.x;
    int node = tid >> 2;
    int t = tid & (NT - 1);
    if (node >= n_nodes) return;

    int begA = (node == 0) ? 0 : curA[node - 1];
    int endA = curA[node];
    int begB = (node == 0) ? 0 : curB[node - 1];
    int endB = curB[node];

    float accA[16], accB[16];
#pragma unroll
    for (int j = 0; j < 16; ++j) { accA[j] = 0.f; accB[j] = 0.f; }

    for (int i = begA + t; i < endA; i += NT) {
        const uint4* p = (const uint4*)(msgA + (size_t)i * 16);
        uint4 v0 = p[0], v1 = p[1];
        unsigned int w0=v0.x,w1=v0.y,w2=v0.z,w3=v0.w,w4=v1.x,w5=v1.y,w6=v1.z,w7=v1.w;
        accA[0]+=bf_lo(w0); accA[1]+=bf_hi(w0); accA[2]+=bf_lo(w1); accA[3]+=bf_hi(w1);
        accA[4]+=bf_lo(w2); accA[5]+=bf_hi(w2); accA[6]+=bf_lo(w3); accA[7]+=bf_hi(w3);
        accA[8]+=bf_lo(w4); accA[9]+=bf_hi(w4); accA[10]+=bf_lo(w5); accA[11]+=bf_hi(w5);
        accA[12]+=bf_lo(w6); accA[13]+=bf_hi(w6); accA[14]+=bf_lo(w7); accA[15]+=bf_hi(w7);
    }
    for (int i = begB + t; i < endB; i += NT) {
        const uint4* p = (const uint4*)(msgB + (size_t)i * 16);
        uint4 v0 = p[0], v1 = p[1];
        unsigned int w0=v0.x,w1=v0.y,w2=v0.z,w3=v0.w,w4=v1.x,w5=v1.y,w6=v1.z,w7=v1.w;
        accB[0]+=bf_lo(w0); accB[1]+=bf_hi(w0); accB[2]+=bf_lo(w1); accB[3]+=bf_hi(w1);
        accB[4]+=bf_lo(w2); accB[5]+=bf_hi(w2); accB[6]+=bf_lo(w3); accB[7]+=bf_hi(w3);
        accB[8]+=bf_lo(w4); accB[9]+=bf_hi(w4); accB[10]+=bf_lo(w5); accB[11]+=bf_hi(w5);
        accB[12]+=bf_lo(w6); accB[13]+=bf_hi(w6); accB[14]+=bf_lo(w7); accB[15]+=bf_hi(w7);
    }

#pragma unroll
    for (int mask = 1; mask < NT; mask <<= 1) {
#pragma unroll
        for (int j = 0; j < 16; ++j) {
            accA[j] += __shfl_xor(accA[j], mask);
            accB[j] += __shfl_xor(accB[j], mask);
        }
    }
    if (t != 0) return;

    int deg = endB - begB;
    float inv = 1.f / fmaxf((float)deg, 1.f);
    float x2[32];
#pragma unroll
    for (int j = 0; j < 16; ++j) x2[j] = accA[j];
#pragma unroll
    for (int j = 0; j < H1; ++j) x2[16 + j] = accB[j];
#pragma unroll
    for (int j = 0; j < H2; ++j) x2[16 + H1 + j] = accB[8 + j] * inv;

    float h[H_IN];
#pragma unroll
    for (int j = 0; j < H_IN; ++j) h[j] = b_red1[j];
#pragma unroll
    for (int k = 0; k < 32; ++k) {
        float xk = x2[k];
#pragma unroll
        for (int j = 0; j < H_IN; ++j) h[j] = fmaf(xk, w_red1[k * H_IN + j], h[j]);
    }
#pragma unroll
    for (int j = 0; j < H_IN; ++j) h[j] = (h[j] >= 0.f) ? h[j] : 0.2f * h[j];

    float o[OUT_NF];
#pragma unroll
    for (int j = 0; j < OUT_NF; ++j) o[j] = b_red2[j];
#pragma unroll
    for (int k = 0; k < H_IN; ++k) {
        float hk = h[k];
#pragma unroll
        for (int j = 0; j < OUT_NF; ++j) o[j] = fmaf(hk, w_red2[k * OUT_NF + j], o[j]);
    }

    bool has_in = (deg > 0);
    float4* po = (float4*)(out + (long)node * OUT_NF);
#pragma unroll
    for (int i = 0; i < 4; ++i) {
        float4 v;
        if (has_in) { v.x=o[4*i+0]; v.y=o[4*i+1]; v.z=o[4*i+2]; v.w=o[4*i+3]; }
        else        { v.x=accA[4*i+0]; v.y=accA[4*i+1]; v.z=accA[4*i+2]; v.w=accA[4*i+3]; }
        po[i] = v;
    }
}

// ===========================================================================
// FALLBACK PATH (round-1, known correct): scatter perm + fused gather-compute
// ===========================================================================
__global__ __launch_bounds__(256) void k_scatter(
    const int* __restrict__ dst_out, const int* __restrict__ dst_in,
    int* __restrict__ off_out, int* __restrict__ off_in,
    int* __restrict__ perm_out, int* __restrict__ perm_in, int n_edges)
{
    int e = blockIdx.x * blockDim.x + threadIdx.x;
    if (e >= n_edges) return;
    int p0 = atomicAdd(&off_out[dst_out[e]], 1);
    perm_out[p0] = e;
    int p1 = atomicAdd(&off_in[dst_in[e]], 1);
    perm_in[p1] = e;
}

__global__ __launch_bounds__(256) void k_node_fused(
    const float* __restrict__ nf,
    const int* __restrict__ src_out, const float* __restrict__ nef_out,
    const int* __restrict__ src_in, const float* __restrict__ nef_in,
    const int* __restrict__ off_out, const int* __restrict__ off_in,
    const int* __restrict__ perm_out, const int* __restrict__ perm_in,
    const float* __restrict__ w_o2i1, const float* __restrict__ b_o2i1,
    const float* __restrict__ w_o2i2, const float* __restrict__ b_o2i2,
    const float* __restrict__ w_i2o1, const float* __restrict__ b_i2o1,
    const float* __restrict__ w_i2o2, const float* __restrict__ b_i2o2,
    const float* __restrict__ w_red1, const float* __restrict__ b_red1,
    const float* __restrict__ w_red2, const float* __restrict__ b_red2,
    float* __restrict__ out, int n_nodes)
{
    int tid = blockIdx.x * blockDim.x + threadIdx.x;
    int node = tid >> 2;
    int t = tid & (NT - 1);
    if (node >= n_nodes) return;

    float xd[IN_NF];
    {
        const float4* p = (const float4*)(nf + (long)node * IN_NF);
#pragma unroll
        for (int i = 0; i < 4; ++i) {
            float4 v = p[i];
            xd[4*i+0]=v.x; xd[4*i+1]=v.y; xd[4*i+2]=v.z; xd[4*i+3]=v.w;
        }
    }
    float hbA[H_IN], hbB[H_IN];
#pragma unroll
    for (int j = 0; j < H_IN; ++j) { hbA[j] = b_o2i1[j]; hbB[j] = b_i2o1[j]; }
#pragma unroll
    for (int k = 0; k < IN_NF; ++k) {
        float xk = xd[k];
#pragma unroll
        for (int j = 0; j < H_IN; ++j) {
            hbA[j] = fmaf(xk, w_o2i1[(IN_NF + k) * H_IN + j], hbA[j]);
            hbB[j] = fmaf(xk, w_i2o1[(IN_NF + k) * H_IN + j], hbB[j]);
        }
    }

    float accA[OUT_NF];
#pragma unroll
    for (int j = 0; j < OUT_NF; ++j) accA[j] = 0.f;
    int begO = (node == 0) ? 0 : off_out[node - 1];
    int endO = off_out[node];
    int localO = 0;
    for (int i = begO + t; i < endO; i += NT) {
        int e = perm_out[i];
        int s = src_out[e];
        float xs[IN_NF], xe[IN_EF];
        {
            const float4* ps = (const float4*)(nf + (long)s * IN_NF);
#pragma unroll
            for (int q = 0; q < 4; ++q) {
                float4 v = ps[q];
                xs[4*q+0]=v.x; xs[4*q+1]=v.y; xs[4*q+2]=v.z; xs[4*q+3]=v.w;
            }
            const float4* pe = (const float4*)(nef_out + (long)e * IN_EF);
#pragma unroll
            for (int q = 0; q < 2; ++q) {
                float4 v = pe[q];
                xe[4*q+0]=v.x; xe[4*q+1]=v.y; xe[4*q+2]=v.z; xe[4*q+3]=v.w;
            }
        }
        float h[H_IN];
#pragma unroll
        for (int j = 0; j < H_IN; ++j) h[j] = hbA[j];
#pragma unroll
        for (int k = 0; k < IN_NF; ++k) {
            float xk = xs[k];
#pragma unroll
            for (int j = 0; j < H_IN; ++j) h[j] = fmaf(xk, w_o2i1[k * H_IN + j], h[j]);
        }
#pragma unroll
        for (int k = 0; k < IN_EF; ++k) {
            float xk = xe[k];
#pragma unroll
            for (int j = 0; j < H_IN; ++j) h[j] = fmaf(xk, w_o2i1[(2*IN_NF + k) * H_IN + j], h[j]);
        }
#pragma unroll
        for (int j = 0; j < H_IN; ++j) h[j] = (h[j] >= 0.f) ? h[j] : 0.2f * h[j];
#pragma unroll
        for (int k = 0; k < H_IN; ++k) {
            float hk = h[k];
#pragma unroll
            for (int j = 0; j < OUT_NF; ++j) accA[j] = fmaf(hk, w_o2i2[k * OUT_NF + j], accA[j]);
        }
        ++localO;
    }
#pragma unroll
    for (int j = 0; j < OUT_NF; ++j) accA[j] = fmaf((float)localO, b_o2i2[j], accA[j]);

    float acc1[H1], acc2[H2];
#pragma unroll
    for (int j = 0; j < H1; ++j) acc1[j] = 0.f;
#pragma unroll
    for (int j = 0; j < H2; ++j) acc2[j] = 0.f;
    int begI = (node == 0) ? 0 : off_in[node - 1];
    int endI = off_in[node];
    int deg = endI - begI;
    for (int i = begI + t; i < endI; i += NT) {
        int e = perm_in[i];
        int s = src_in[e];
        float xs[IN_NF], xe[IN_EF];
        {
            const float4* ps = (const float4*)(nf + (long)s * IN_NF);
#pragma unroll
            for (int q = 0; q < 4; ++q) {
                float4 v = ps[q];
                xs[4*q+0]=v.x; xs[4*q+1]=v.y; xs[4*q+2]=v.z; xs[4*q+3]=v.w;
            }
            const float4* pe = (const float4*)(nef_in + (long)e * IN_EF);
#pragma unroll
            for (int q = 0; q < 2; ++q) {
                float4 v = pe[q];
                xe[4*q+0]=v.x; xe[4*q+1]=v.y; xe[4*q+2]=v.z; xe[4*q+3]=v.w;
            }
        }
        float h[H_IN];
#pragma unroll
        for (int j = 0; j < H_IN; ++j) h[j] = hbB[j];
#pragma unroll
        for (int k = 0; k < IN_NF; ++k) {
            float xk = xs[k];
#pragma unroll
            for (int j = 0; j < H_IN; ++j) h[j] = fmaf(xk, w_i2o1[k * H_IN + j], h[j]);
        }
#pragma unroll
        for (int k = 0; k < IN_EF; ++k) {
            float xk = xe[k];
#pragma unroll
            for (int j = 0; j < H_IN; ++j) h[j] = fmaf(xk, w_i2o1[(2*IN_NF + k) * H_IN + j], h[j]);
        }
#pragma unroll
        for (int j = 0; j < H_IN; ++j) h[j] = (h[j] >= 0.f) ? h[j] : 0.2f * h[j];

        const int M = 1 + H1 + H2;
        float o[17];
#pragma unroll
        for (int j = 0; j < M; ++j) o[j] = b_i2o2[j];
#pragma unroll
        for (int k = 0; k < H_IN; ++k) {
            float hk = h[k];
#pragma unroll
            for (int j = 0; j < M; ++j) o[j] = fmaf(hk, w_i2o2[k * M + j], o[j]);
        }
        float gate = 1.f / (1.f + __expf(-o[0]));
#pragma unroll
        for (int j = 0; j < H1; ++j) acc1[j] = fmaf(o[1 + j], gate, acc1[j]);
#pragma unroll
        for (int j = 0; j < H2; ++j) acc2[j] = fmaf(o[1 + H1 + j], gate, acc2[j]);
    }

#pragma unroll
    for (int mask = 1; mask < NT; mask <<= 1) {
#pragma unroll
        for (int j = 0; j < OUT_NF; ++j) accA[j] += __shfl_xor(accA[j], mask);
#pragma unroll
        for (int j = 0; j < H1; ++j) acc1[j] += __shfl_xor(acc1[j], mask);
#pragma unroll
        for (int j = 0; j < H2; ++j) acc2[j] += __shfl_xor(acc2[j], mask);
    }
    if (t != 0) return;

    float inv = 1.f / fmaxf((float)deg, 1.f);
    float x2[32];
#pragma unroll
    for (int j = 0; j < OUT_NF; ++j) x2[j] = accA[j];
#pragma unroll
    for (int j = 0; j < H1; ++j) x2[OUT_NF + j] = acc1[j];
#pragma unroll
    for (int j = 0; j < H2; ++j) x2[OUT_NF + H1 + j] = acc2[j] * inv;

    float h[H_IN];
#pragma unroll
    for (int j = 0; j < H_IN; ++j) h[j] = b_red1[j];
#pragma unroll
    for (int k = 0; k < 32; ++k) {
        float xk = x2[k];
#pragma unroll
        for (int j = 0; j < H_IN; ++j) h[j] = fmaf(xk, w_red1[k * H_IN + j], h[j]);
    }
#pragma unroll
    for (int j = 0; j < H_IN; ++j) h[j] = (h[j] >= 0.f) ? h[j] : 0.2f * h[j];

    float o[OUT_NF];
#pragma unroll
    for (int j = 0; j < OUT_NF; ++j) o[j] = b_red2[j];
#pragma unroll
    for (int k = 0; k < H_IN; ++k) {
        float hk = h[k];
#pragma unroll
        for (int j = 0; j < OUT_NF; ++j) o[j] = fmaf(hk, w_red2[k * OUT_NF + j], o[j]);
    }

    bool has_in = (deg > 0);
    float4* po = (float4*)(out + (long)node * OUT_NF);
#pragma unroll
    for (int i = 0; i < 4; ++i) {
        float4 v;
        if (has_in) { v.x=o[4*i+0]; v.y=o[4*i+1]; v.z=o[4*i+2]; v.w=o[4*i+3]; }
        else        { v.x=accA[4*i+0]; v.y=accA[4*i+1]; v.z=accA[4*i+2]; v.w=accA[4*i+3]; }
        po[i] = v;
    }
}

extern "C" void kernel_launch(void* const* d_in, const int* in_sizes, int n_in,
                              void* d_out, int out_size, void* d_ws, size_t ws_size,
                              hipStream_t stream) {
    const float* nf      = (const float*)d_in[0];
    const int*   src_out = (const int*)d_in[1];
    const int*   dst_out = (const int*)d_in[2];
    const float* nef_out = (const float*)d_in[3];
    const int*   src_in  = (const int*)d_in[4];
    const int*   dst_in  = (const int*)d_in[5];
    const float* nef_in  = (const float*)d_in[6];
    const float* w_o2i1  = (const float*)d_in[7];
    const float* b_o2i1  = (const float*)d_in[8];
    const float* w_o2i2  = (const float*)d_in[9];
    const float* b_o2i2  = (const float*)d_in[10];
    const float* w_i2o1  = (const float*)d_in[11];
    const float* b_i2o1  = (const float*)d_in[12];
    const float* w_i2o2  = (const float*)d_in[13];
    const float* b_i2o2  = (const float*)d_in[14];
    const float* w_red1  = (const float*)d_in[15];
    const float* b_red1  = (const float*)d_in[16];
    const float* w_red2  = (const float*)d_in[17];
    const float* b_red2  = (const float*)d_in[18];

    int n_nodes = in_sizes[0] / IN_NF;
    int n_edges = in_sizes[1];
    float* out = (float*)d_out;

    dim3 blk(256);
    dim3 egrid((n_edges + 255) / 256);
    dim3 hgrid((n_edges / 4 + 256) / 256 + 1);
    dim3 ngrid(((size_t)n_nodes * NT + 255) / 256);
    dim3 sgrid(2 * SCAN_NB);

    size_t off_bytes = (size_t)2 * n_nodes * sizeof(int);
    size_t nf16_bytes = (size_t)n_nodes * 16 * sizeof(unsigned short);
    size_t msg_bytes = (size_t)n_edges * 16 * sizeof(unsigned short);
    size_t need_fast = off_bytes + nf16_bytes + 2 * msg_bytes + 256;

    if (ws_size >= need_fast) {
        int* curA = (int*)d_ws;
        int* curB = curA + n_nodes;
        unsigned short* nf16 = (unsigned short*)(curB + n_nodes);
        unsigned short* msgA = nf16 + (size_t)n_nodes * 16;
        unsigned short* msgB = msgA + (size_t)n_edges * 16;
        // block-sum scratch aliases into msgA (dead until k_edge_a runs)
        int* bsum = (int*)msgA;

        int nb_conv = (n_nodes + 255) / 256;
        int nb_hist = (n_edges / 4 + 256) / 256 + 1;
        dim3 pgrid(nb_conv + nb_hist);

        int T = EDGE_BLOCKS * 256;
        dim3 edge_grid(EDGE_BLOCKS);

        hipMemsetAsync(d_ws, 0, off_bytes, stream);
        k_pre<<<pgrid, blk, 0, stream>>>(nf, nf16, n_nodes, dst_out, dst_in,
                                         curA, curB, n_edges, nb_conv);
        k_scan_partial<<<sgrid, blk, 0, stream>>>(curA, curB, n_nodes, bsum);
        k_scan_bsum<<<dim3(1), dim3(64), 0, stream>>>(bsum);
        k_scan_final<<<sgrid, blk, 0, stream>>>(curA, curB, n_nodes, bsum);
        k_edge_a<<<edge_grid, blk, 0, stream>>>(nf16, src_out, dst_out, nef_out,
                                                w_o2i1, b_o2i1, w_o2i2, b_o2i2,
                                                curA, msgA, n_edges, T);
        k_edge_b<<<edge_grid, blk, 0, stream>>>(nf16, src_in, dst_in, nef_in,
                                                w_i2o1, b_i2o1, w_i2o2, b_i2o2,
                                                curB, msgB, n_edges, T);
        k_gather<<<ngrid, blk, 0, stream>>>(curA, curB, msgA, msgB,
                                            w_red1, b_red1, w_red2, b_red2,
                                            out, n_nodes);
    } else {
        int* off_out  = (int*)d_ws;
        int* off_in   = off_out + n_nodes;
        int* perm_out = off_in + n_nodes;
        int* perm_in  = perm_out + n_edges;
        int* bsum = perm_out;  // dead until k_scatter

        hipMemsetAsync(d_ws, 0, off_bytes, stream);
        k_hist<<<hgrid, blk, 0, stream>>>(dst_out, dst_in, off_out, off_in, n_edges);
        k_scan_partial<<<sgrid, blk, 0, stream>>>(off_out, off_in, n_nodes, bsum);
        k_scan_bsum<<<dim3(1), dim3(64), 0, stream>>>(bsum);
        k_scan_final<<<sgrid, blk, 0, stream>>>(off_out, off_in, n_nodes, bsum);
        k_scatter<<<egrid, blk, 0, stream>>>(dst_out, dst_in, off_out, off_in,
                                             perm_out, perm_in, n_edges);
        k_node_fused<<<ngrid, blk, 0, stream>>>(nf, src_out, nef_out, src_in, nef_in,
                                          off_out, off_in, perm_out, perm_in,
                                          w_o2i1, b_o2i1, w_o2i2, b_o2i2,
                                          w_i2o1, b_i2o1, w_i2o2, b_i2o2,
                                          w_red1, b_red1, w_red2, b_red2,
                                          out, n_nodes);
    }
}

// Round 8
// 458.538 us; speedup vs baseline: 1.6310x; 1.6310x over previous
//
#include <hip/hip_runtime.h>
#include <math.h>

#define IN_NF 16
#define IN_EF 8
#define OUT_NF 16
#define H1 8
#define H2 8
#define H_IN 16
#define D_IN 40   // 2*IN_NF + IN_EF
#define NT 4      // threads cooperating per node (gather)
#define SCAN_NB 128  // scan blocks per array

typedef unsigned int uivec4 __attribute__((ext_vector_type(4)));

// ---------------------------------------------------------------------------
// bf16 helpers (RNE)
// ---------------------------------------------------------------------------
__device__ __forceinline__ unsigned int f2bf_bits(float f) {
    unsigned int u = __float_as_uint(f);
    u += 0x7FFFu + ((u >> 16) & 1u);
    return u >> 16;
}
__device__ __forceinline__ float bf_lo(unsigned int w) { return __uint_as_float(w << 16); }
__device__ __forceinline__ float bf_hi(unsigned int w) { return __uint_as_float(w & 0xFFFF0000u); }

// ---------------------------------------------------------------------------
// Fused prepass: blocks [0, nb_conv) convert nf -> bf16; rest do the
// destination histogram for both graphs (int atomics, int4 loads).
// ---------------------------------------------------------------------------
__global__ __launch_bounds__(256) void k_pre(
    const float* __restrict__ nf, unsigned short* __restrict__ nf16, int n_nodes,
    const int* __restrict__ dst_out, const int* __restrict__ dst_in,
    int* __restrict__ curA, int* __restrict__ curB, int n_edges, int nb_conv)
{
    if ((int)blockIdx.x < nb_conv) {
        int n = blockIdx.x * 256 + threadIdx.x;
        if (n >= n_nodes) return;
        const float4* p = (const float4*)(nf + (long)n * IN_NF);
        unsigned int w[8];
#pragma unroll
        for (int q = 0; q < 4; ++q) {
            float4 v = p[q];
            w[2*q+0] = f2bf_bits(v.x) | (f2bf_bits(v.y) << 16);
            w[2*q+1] = f2bf_bits(v.z) | (f2bf_bits(v.w) << 16);
        }
        uint4* o = (uint4*)(nf16 + (size_t)n * 16);
        o[0] = make_uint4(w[0], w[1], w[2], w[3]);
        o[1] = make_uint4(w[4], w[5], w[6], w[7]);
    } else {
        int i = ((blockIdx.x - nb_conv) * 256 + threadIdx.x) * 4;
        if (i + 3 < n_edges) {
            int4 a = *(const int4*)(dst_out + i);
            atomicAdd(&curA[a.x], 1); atomicAdd(&curA[a.y], 1);
            atomicAdd(&curA[a.z], 1); atomicAdd(&curA[a.w], 1);
            int4 b = *(const int4*)(dst_in + i);
            atomicAdd(&curB[b.x], 1); atomicAdd(&curB[b.y], 1);
            atomicAdd(&curB[b.z], 1); atomicAdd(&curB[b.w], 1);
        } else {
            for (int e = i; e < n_edges; ++e) {
                atomicAdd(&curA[dst_out[e]], 1);
                atomicAdd(&curB[dst_in[e]], 1);
            }
        }
    }
}

// standalone hist for the fallback path
__global__ __launch_bounds__(256) void k_hist(
    const int* __restrict__ dst_out, const int* __restrict__ dst_in,
    int* __restrict__ off_out, int* __restrict__ off_in, int n_edges)
{
    int i = (blockIdx.x * blockDim.x + threadIdx.x) * 4;
    if (i + 3 < n_edges) {
        int4 a = *(const int4*)(dst_out + i);
        atomicAdd(&off_out[a.x], 1); atomicAdd(&off_out[a.y], 1);
        atomicAdd(&off_out[a.z], 1); atomicAdd(&off_out[a.w], 1);
        int4 b = *(const int4*)(dst_in + i);
        atomicAdd(&off_in[b.x], 1); atomicAdd(&off_in[b.y], 1);
        atomicAdd(&off_in[b.z], 1); atomicAdd(&off_in[b.w], 1);
    } else {
        for (int e = i; e < n_edges; ++e) {
            atomicAdd(&off_out[dst_out[e]], 1);
            atomicAdd(&off_in[dst_in[e]], 1);
        }
    }
}

// ---------------------------------------------------------------------------
// Hierarchical exclusive scan over two adjacent arrays a0,a1 (n each).
// ---------------------------------------------------------------------------
__global__ __launch_bounds__(256) void k_scan_partial(
    const int* __restrict__ a0, const int* __restrict__ a1, int n,
    int* __restrict__ bsum)
{
    int arr = blockIdx.x >> 7;           // /SCAN_NB
    int blk = blockIdx.x & (SCAN_NB - 1);
    const int* a = arr ? a1 : a0;
    int chunk = (n + SCAN_NB - 1) / SCAN_NB;
    int beg = blk * chunk;
    int end = min(beg + chunk, n);
    int s = 0;
    for (int i = beg + threadIdx.x; i < end; i += 256) s += a[i];
    __shared__ int sm[256];
    int t = threadIdx.x;
    sm[t] = s;
    __syncthreads();
    for (int d = 128; d > 0; d >>= 1) {
        if (t < d) sm[t] += sm[t + d];
        __syncthreads();
    }
    if (t == 0) bsum[arr * SCAN_NB + blk] = sm[0];
}

__global__ __launch_bounds__(64) void k_scan_bsum(int* __restrict__ bsum)
{
    int arr = threadIdx.x;
    if (arr >= 2) return;
    int run = 0;
    for (int i = 0; i < SCAN_NB; ++i) {
        int v = bsum[arr * SCAN_NB + i];
        bsum[arr * SCAN_NB + i] = run;
        run += v;
    }
}

__global__ __launch_bounds__(256) void k_scan_final(
    int* __restrict__ a0, int* __restrict__ a1, int n,
    const int* __restrict__ bsum)
{
    int arr = blockIdx.x >> 7;
    int blk = blockIdx.x & (SCAN_NB - 1);
    int* a = arr ? a1 : a0;
    int chunk = (n + SCAN_NB - 1) / SCAN_NB;
    int beg = blk * chunk;
    int end = min(beg + chunk, n);
    int t = threadIdx.x;
    __shared__ int sm[256];
    __shared__ int carry_sm;
    if (t == 0) carry_sm = bsum[arr * SCAN_NB + blk];
    __syncthreads();
    for (int base = beg; base < end; base += 256) {
        int i = base + t;
        int v = (i < end) ? a[i] : 0;
        sm[t] = v;
        __syncthreads();
        for (int d = 1; d < 256; d <<= 1) {
            int u = (t >= d) ? sm[t - d] : 0;
            __syncthreads();
            sm[t] += u;
            __syncthreads();
        }
        int carry = carry_sm;
        if (i < end) a[i] = carry + sm[t] - v;   // exclusive
        __syncthreads();
        if (t == 0) carry_sm = carry + sm[255];
        __syncthreads();
    }
}

// ---------------------------------------------------------------------------
// Fused edge kernel: blocks [0,nbe) process graph A (MLP_msg_o2i), blocks
// [nbe,2*nbe) graph B (MLP_msg_i2o + gate). 1 edge/thread (round-4 structure:
// best measured). Changes vs round 4: cursor atomic issued BEFORE the MLP so
// its RTT hides under ~1790 cyc of FMA; message stores are non-temporal.
// ---------------------------------------------------------------------------
__global__ __launch_bounds__(256, 4) void k_edges(
    const unsigned short* __restrict__ nf16,
    const int* __restrict__ srcA, const int* __restrict__ dstA,
    const float* __restrict__ nefA,
    const int* __restrict__ srcB, const int* __restrict__ dstB,
    const float* __restrict__ nefB,
    const float* __restrict__ W1A, const float* __restrict__ B1A,
    const float* __restrict__ W2A, const float* __restrict__ B2A,
    const float* __restrict__ W1B, const float* __restrict__ B1B,
    const float* __restrict__ W2B, const float* __restrict__ B2B,
    int* __restrict__ curA, int* __restrict__ curB,
    unsigned short* __restrict__ msgA, unsigned short* __restrict__ msgB,
    int n_edges, int nbe)
{
    bool isA = (int)blockIdx.x < nbe;
    int bid = isA ? (int)blockIdx.x : (int)blockIdx.x - nbe;
    int e = bid * 256 + (int)threadIdx.x;
    if (e >= n_edges) return;

    const int* src = isA ? srcA : srcB;
    const int* dst = isA ? dstA : dstB;
    const float* nef = isA ? nefA : nefB;
    const float* W1 = isA ? W1A : W1B;
    const float* B1 = isA ? B1A : B1B;
    int* cursor = isA ? curA : curB;
    unsigned short* msg = isA ? msgA : msgB;

    int s = src[e];
    int d = dst[e];

    // ---- issue all gathers
    const uint4* pS = (const uint4*)(nf16 + (size_t)s * 16);
    uint4 Sa = pS[0], Sb = pS[1];
    const uint4* pD = (const uint4*)(nf16 + (size_t)d * 16);
    uint4 Da = pD[0], Db = pD[1];
    const float4* pN = (const float4*)(nef + (size_t)e * IN_EF);
    float4 Na = pN[0], Nb = pN[1];

    // ---- early atomic: RTT hides under the MLP below
    int slot = atomicAdd(&cursor[d], 1);

    // ---- layer 1 (shared 40->16 shape), operands unpacked from bf16 words
    float h[H_IN];
#pragma unroll
    for (int j = 0; j < H_IN; ++j) h[j] = B1[j];
    {
        unsigned int wS[8] = {Sa.x,Sa.y,Sa.z,Sa.w,Sb.x,Sb.y,Sb.z,Sb.w};
        unsigned int wD[8] = {Da.x,Da.y,Da.z,Da.w,Db.x,Db.y,Db.z,Db.w};
#pragma unroll
        for (int w = 0; w < 8; ++w) {
            float a0 = bf_lo(wS[w]), a1 = bf_hi(wS[w]);
            float b0 = bf_lo(wD[w]), b1 = bf_hi(wD[w]);
            const float* r0 = W1 + (2*w) * H_IN;
            const float* r1 = W1 + (2*w+1) * H_IN;
            const float* r2 = W1 + (IN_NF + 2*w) * H_IN;
            const float* r3 = W1 + (IN_NF + 2*w+1) * H_IN;
#pragma unroll
            for (int j = 0; j < H_IN; ++j) {
                h[j] = fmaf(a0, r0[j], h[j]);
                h[j] = fmaf(a1, r1[j], h[j]);
                h[j] = fmaf(b0, r2[j], h[j]);
                h[j] = fmaf(b1, r3[j], h[j]);
            }
        }
        float nv[8] = {Na.x,Na.y,Na.z,Na.w,Nb.x,Nb.y,Nb.z,Nb.w};
#pragma unroll
        for (int k = 0; k < IN_EF; ++k) {
            const float* r = W1 + (2*IN_NF + k) * H_IN;
            float a0 = nv[k];
#pragma unroll
            for (int j = 0; j < H_IN; ++j) h[j] = fmaf(a0, r[j], h[j]);
        }
    }
#pragma unroll
    for (int j = 0; j < H_IN; ++j) h[j] = (h[j] >= 0.f) ? h[j] : 0.2f * h[j];

    // ---- layer 2 diverges per graph (wave-uniform branch)
    unsigned int w[8];
    if (isA) {
        float o[OUT_NF];
#pragma unroll
        for (int j = 0; j < OUT_NF; ++j) o[j] = B2A[j];
#pragma unroll
        for (int k = 0; k < H_IN; ++k) {
            float hk = h[k];
            const float* r = W2A + k * OUT_NF;
#pragma unroll
            for (int j = 0; j < OUT_NF; ++j) o[j] = fmaf(hk, r[j], o[j]);
        }
#pragma unroll
        for (int q = 0; q < 8; ++q)
            w[q] = f2bf_bits(o[2*q]) | (f2bf_bits(o[2*q+1]) << 16);
    } else {
        const int M = 1 + H1 + H2; // 17
        float o[17];
#pragma unroll
        for (int j = 0; j < M; ++j) o[j] = B2B[j];
#pragma unroll
        for (int k = 0; k < H_IN; ++k) {
            float hk = h[k];
            const float* r = W2B + k * M;
#pragma unroll
            for (int j = 0; j < M; ++j) o[j] = fmaf(hk, r[j], o[j]);
        }
        float g = 1.f / (1.f + __expf(-o[0]));
#pragma unroll
        for (int q = 0; q < 8; ++q)
            w[q] = f2bf_bits(o[1+2*q] * g) | (f2bf_bits(o[2+2*q] * g) << 16);
    }

    uivec4* pm = (uivec4*)(msg + (size_t)slot * 16);
    uivec4 v0 = {w[0], w[1], w[2], w[3]};
    uivec4 v1 = {w[4], w[5], w[6], w[7]};
    __builtin_nontemporal_store(v0, pm);
    __builtin_nontemporal_store(v1, pm + 1);
}

// ---------------------------------------------------------------------------
// Gather: NT lanes/node stream contiguous bf16 messages, reduce, reduce-MLP.
// ---------------------------------------------------------------------------
__global__ __launch_bounds__(256, 4) void k_gather(
    const int* __restrict__ curA, const int* __restrict__ curB,
    const unsigned short* __restrict__ msgA, const unsigned short* __restrict__ msgB,
    const float* __restrict__ w_red1, const float* __restrict__ b_red1,
    const float* __restrict__ w_red2, const float* __restrict__ b_red2,
    float* __restrict__ out, int n_nodes)
{
    int tid = blockIdx.x * blockDim.x + threadIdx.x;
    int node = tid >> 2;
    int t = tid & (NT - 1);
    if (node >= n_nodes) return;

    int begA = (node == 0) ? 0 : curA[node - 1];
    int endA = curA[node];
    int begB = (node == 0) ? 0 : curB[node - 1];
    int endB = curB[node];

    float accA[16], accB[16];
#pragma unroll
    for (int j = 0; j < 16; ++j) { accA[j] = 0.f; accB[j] = 0.f; }

    for (int i = begA + t; i < endA; i += NT) {
        const uint4* p = (const uint4*)(msgA + (size_t)i * 16);
        uint4 v0 = p[0], v1 = p[1];
        unsigned int w0=v0.x,w1=v0.y,w2=v0.z,w3=v0.w,w4=v1.x,w5=v1.y,w6=v1.z,w7=v1.w;
        accA[0]+=bf_lo(w0); accA[1]+=bf_hi(w0); accA[2]+=bf_lo(w1); accA[3]+=bf_hi(w1);
        accA[4]+=bf_lo(w2); accA[5]+=bf_hi(w2); accA[6]+=bf_lo(w3); accA[7]+=bf_hi(w3);
        accA[8]+=bf_lo(w4); accA[9]+=bf_hi(w4); accA[10]+=bf_lo(w5); accA[11]+=bf_hi(w5);
        accA[12]+=bf_lo(w6); accA[13]+=bf_hi(w6); accA[14]+=bf_lo(w7); accA[15]+=bf_hi(w7);
    }
    for (int i = begB + t; i < endB; i += NT) {
        const uint4* p = (const uint4*)(msgB + (size_t)i * 16);
        uint4 v0 = p[0], v1 = p[1];
        unsigned int w0=v0.x,w1=v0.y,w2=v0.z,w3=v0.w,w4=v1.x,w5=v1.y,w6=v1.z,w7=v1.w;
        accB[0]+=bf_lo(w0); accB[1]+=bf_hi(w0); accB[2]+=bf_lo(w1); accB[3]+=bf_hi(w1);
        accB[4]+=bf_lo(w2); accB[5]+=bf_hi(w2); accB[6]+=bf_lo(w3); accB[7]+=bf_hi(w3);
        accB[8]+=bf_lo(w4); accB[9]+=bf_hi(w4); accB[10]+=bf_lo(w5); accB[11]+=bf_hi(w5);
        accB[12]+=bf_lo(w6); accB[13]+=bf_hi(w6); accB[14]+=bf_lo(w7); accB[15]+=bf_hi(w7);
    }

#pragma unroll
    for (int mask = 1; mask < NT; mask <<= 1) {
#pragma unroll
        for (int j = 0; j < 16; ++j) {
            accA[j] += __shfl_xor(accA[j], mask);
            accB[j] += __shfl_xor(accB[j], mask);
        }
    }
    if (t != 0) return;

    int deg = endB - begB;
    float inv = 1.f / fmaxf((float)deg, 1.f);
    float x2[32];
#pragma unroll
    for (int j = 0; j < 16; ++j) x2[j] = accA[j];
#pragma unroll
    for (int j = 0; j < H1; ++j) x2[16 + j] = accB[j];
#pragma unroll
    for (int j = 0; j < H2; ++j) x2[16 + H1 + j] = accB[8 + j] * inv;

    float h[H_IN];
#pragma unroll
    for (int j = 0; j < H_IN; ++j) h[j] = b_red1[j];
#pragma unroll
    for (int k = 0; k < 32; ++k) {
        float xk = x2[k];
#pragma unroll
        for (int j = 0; j < H_IN; ++j) h[j] = fmaf(xk, w_red1[k * H_IN + j], h[j]);
    }
#pragma unroll
    for (int j = 0; j < H_IN; ++j) h[j] = (h[j] >= 0.f) ? h[j] : 0.2f * h[j];

    float o[OUT_NF];
#pragma unroll
    for (int j = 0; j < OUT_NF; ++j) o[j] = b_red2[j];
#pragma unroll
    for (int k = 0; k < H_IN; ++k) {
        float hk = h[k];
#pragma unroll
        for (int j = 0; j < OUT_NF; ++j) o[j] = fmaf(hk, w_red2[k * OUT_NF + j], o[j]);
    }

    bool has_in = (deg > 0);
    float4* po = (float4*)(out + (long)node * OUT_NF);
#pragma unroll
    for (int i = 0; i < 4; ++i) {
        float4 v;
        if (has_in) { v.x=o[4*i+0]; v.y=o[4*i+1]; v.z=o[4*i+2]; v.w=o[4*i+3]; }
        else        { v.x=accA[4*i+0]; v.y=accA[4*i+1]; v.z=accA[4*i+2]; v.w=accA[4*i+3]; }
        po[i] = v;
    }
}

// ===========================================================================
// FALLBACK PATH (round-1, known correct): scatter perm + fused gather-compute
// ===========================================================================
__global__ __launch_bounds__(256) void k_scatter(
    const int* __restrict__ dst_out, const int* __restrict__ dst_in,
    int* __restrict__ off_out, int* __restrict__ off_in,
    int* __restrict__ perm_out, int* __restrict__ perm_in, int n_edges)
{
    int e = blockIdx.x * blockDim.x + threadIdx.x;
    if (e >= n_edges) return;
    int p0 = atomicAdd(&off_out[dst_out[e]], 1);
    perm_out[p0] = e;
    int p1 = atomicAdd(&off_in[dst_in[e]], 1);
    perm_in[p1] = e;
}

__global__ __launch_bounds__(256) void k_node_fused(
    const float* __restrict__ nf,
    const int* __restrict__ src_out, const float* __restrict__ nef_out,
    const int* __restrict__ src_in, const float* __restrict__ nef_in,
    const int* __restrict__ off_out, const int* __restrict__ off_in,
    const int* __restrict__ perm_out, const int* __restrict__ perm_in,
    const float* __restrict__ w_o2i1, const float* __restrict__ b_o2i1,
    const float* __restrict__ w_o2i2, const float* __restrict__ b_o2i2,
    const float* __restrict__ w_i2o1, const float* __restrict__ b_i2o1,
    const float* __restrict__ w_i2o2, const float* __restrict__ b_i2o2,
    const float* __restrict__ w_red1, const float* __restrict__ b_red1,
    const float* __restrict__ w_red2, const float* __restrict__ b_red2,
    float* __restrict__ out, int n_nodes)
{
    int tid = blockIdx.x * blockDim.x + threadIdx.x;
    int node = tid >> 2;
    int t = tid & (NT - 1);
    if (node >= n_nodes) return;

    float xd[IN_NF];
    {
        const float4* p = (const float4*)(nf + (long)node * IN_NF);
#pragma unroll
        for (int i = 0; i < 4; ++i) {
            float4 v = p[i];
            xd[4*i+0]=v.x; xd[4*i+1]=v.y; xd[4*i+2]=v.z; xd[4*i+3]=v.w;
        }
    }
    float hbA[H_IN], hbB[H_IN];
#pragma unroll
    for (int j = 0; j < H_IN; ++j) { hbA[j] = b_o2i1[j]; hbB[j] = b_i2o1[j]; }
#pragma unroll
    for (int k = 0; k < IN_NF; ++k) {
        float xk = xd[k];
#pragma unroll
        for (int j = 0; j < H_IN; ++j) {
            hbA[j] = fmaf(xk, w_o2i1[(IN_NF + k) * H_IN + j], hbA[j]);
            hbB[j] = fmaf(xk, w_i2o1[(IN_NF + k) * H_IN + j], hbB[j]);
        }
    }

    float accA[OUT_NF];
#pragma unroll
    for (int j = 0; j < OUT_NF; ++j) accA[j] = 0.f;
    int begO = (node == 0) ? 0 : off_out[node - 1];
    int endO = off_out[node];
    int localO = 0;
    for (int i = begO + t; i < endO; i += NT) {
        int e = perm_out[i];
        int s = src_out[e];
        float xs[IN_NF], xe[IN_EF];
        {
            const float4* ps = (const float4*)(nf + (long)s * IN_NF);
#pragma unroll
            for (int q = 0; q < 4; ++q) {
                float4 v = ps[q];
                xs[4*q+0]=v.x; xs[4*q+1]=v.y; xs[4*q+2]=v.z; xs[4*q+3]=v.w;
            }
            const float4* pe = (const float4*)(nef_out + (long)e * IN_EF);
#pragma unroll
            for (int q = 0; q < 2; ++q) {
                float4 v = pe[q];
                xe[4*q+0]=v.x; xe[4*q+1]=v.y; xe[4*q+2]=v.z; xe[4*q+3]=v.w;
            }
        }
        float h[H_IN];
#pragma unroll
        for (int j = 0; j < H_IN; ++j) h[j] = hbA[j];
#pragma unroll
        for (int k = 0; k < IN_NF; ++k) {
            float xk = xs[k];
#pragma unroll
            for (int j = 0; j < H_IN; ++j) h[j] = fmaf(xk, w_o2i1[k * H_IN + j], h[j]);
        }
#pragma unroll
        for (int k = 0; k < IN_EF; ++k) {
            float xk = xe[k];
#pragma unroll
            for (int j = 0; j < H_IN; ++j) h[j] = fmaf(xk, w_o2i1[(2*IN_NF + k) * H_IN + j], h[j]);
        }
#pragma unroll
        for (int j = 0; j < H_IN; ++j) h[j] = (h[j] >= 0.f) ? h[j] : 0.2f * h[j];
#pragma unroll
        for (int k = 0; k < H_IN; ++k) {
            float hk = h[k];
#pragma unroll
            for (int j = 0; j < OUT_NF; ++j) accA[j] = fmaf(hk, w_o2i2[k * OUT_NF + j], accA[j]);
        }
        ++localO;
    }
#pragma unroll
    for (int j = 0; j < OUT_NF; ++j) accA[j] = fmaf((float)localO, b_o2i2[j], accA[j]);

    float acc1[H1], acc2[H2];
#pragma unroll
    for (int j = 0; j < H1; ++j) acc1[j] = 0.f;
#pragma unroll
    for (int j = 0; j < H2; ++j) acc2[j] = 0.f;
    int begI = (node == 0) ? 0 : off_in[node - 1];
    int endI = off_in[node];
    int deg = endI - begI;
    for (int i = begI + t; i < endI; i += NT) {
        int e = perm_in[i];
        int s = src_in[e];
        float xs[IN_NF], xe[IN_EF];
        {
            const float4* ps = (const float4*)(nf + (long)s * IN_NF);
#pragma unroll
            for (int q = 0; q < 4; ++q) {
                float4 v = ps[q];
                xs[4*q+0]=v.x; xs[4*q+1]=v.y; xs[4*q+2]=v.z; xs[4*q+3]=v.w;
            }
            const float4* pe = (const float4*)(nef_in + (long)e * IN_EF);
#pragma unroll
            for (int q = 0; q < 2; ++q) {
                float4 v = pe[q];
                xe[4*q+0]=v.x; xe[4*q+1]=v.y; xe[4*q+2]=v.z; xe[4*q+3]=v.w;
            }
        }
        float h[H_IN];
#pragma unroll
        for (int j = 0; j < H_IN; ++j) h[j] = hbB[j];
#pragma unroll
        for (int k = 0; k < IN_NF; ++k) {
            float xk = xs[k];
#pragma unroll
            for (int j = 0; j < H_IN; ++j) h[j] = fmaf(xk, w_i2o1[k * H_IN + j], h[j]);
        }
#pragma unroll
        for (int k = 0; k < IN_EF; ++k) {
            float xk = xe[k];
#pragma unroll
            for (int j = 0; j < H_IN; ++j) h[j] = fmaf(xk, w_i2o1[(2*IN_NF + k) * H_IN + j], h[j]);
        }
#pragma unroll
        for (int j = 0; j < H_IN; ++j) h[j] = (h[j] >= 0.f) ? h[j] : 0.2f * h[j];

        const int M = 1 + H1 + H2;
        float o[17];
#pragma unroll
        for (int j = 0; j < M; ++j) o[j] = b_i2o2[j];
#pragma unroll
        for (int k = 0; k < H_IN; ++k) {
            float hk = h[k];
#pragma unroll
            for (int j = 0; j < M; ++j) o[j] = fmaf(hk, w_i2o2[k * M + j], o[j]);
        }
        float gate = 1.f / (1.f + __expf(-o[0]));
#pragma unroll
        for (int j = 0; j < H1; ++j) acc1[j] = fmaf(o[1 + j], gate, acc1[j]);
#pragma unroll
        for (int j = 0; j < H2; ++j) acc2[j] = fmaf(o[1 + H1 + j], gate, acc2[j]);
    }

#pragma unroll
    for (int mask = 1; mask < NT; mask <<= 1) {
#pragma unroll
        for (int j = 0; j < OUT_NF; ++j) accA[j] += __shfl_xor(accA[j], mask);
#pragma unroll
        for (int j = 0; j < H1; ++j) acc1[j] += __shfl_xor(acc1[j], mask);
#pragma unroll
        for (int j = 0; j < H2; ++j) acc2[j] += __shfl_xor(acc2[j], mask);
    }
    if (t != 0) return;

    float inv = 1.f / fmaxf((float)deg, 1.f);
    float x2[32];
#pragma unroll
    for (int j = 0; j < OUT_NF; ++j) x2[j] = accA[j];
#pragma unroll
    for (int j = 0; j < H1; ++j) x2[OUT_NF + j] = acc1[j];
#pragma unroll
    for (int j = 0; j < H2; ++j) x2[OUT_NF + H1 + j] = acc2[j] * inv;

    float h[H_IN];
#pragma unroll
    for (int j = 0; j < H_IN; ++j) h[j] = b_red1[j];
#pragma unroll
    for (int k = 0; k < 32; ++k) {
        float xk = x2[k];
#pragma unroll
        for (int j = 0; j < H_IN; ++j) h[j] = fmaf(xk, w_red1[k * H_IN + j], h[j]);
    }
#pragma unroll
    for (int j = 0; j < H_IN; ++j) h[j] = (h[j] >= 0.f) ? h[j] : 0.2f * h[j];

    float o[OUT_NF];
#pragma unroll
    for (int j = 0; j < OUT_NF; ++j) o[j] = b_red2[j];
#pragma unroll
    for (int k = 0; k < H_IN; ++k) {
        float hk = h[k];
#pragma unroll
        for (int j = 0; j < OUT_NF; ++j) o[j] = fmaf(hk, w_red2[k * OUT_NF + j], o[j]);
    }

    bool has_in = (deg > 0);
    float4* po = (float4*)(out + (long)node * OUT_NF);
#pragma unroll
    for (int i = 0; i < 4; ++i) {
        float4 v;
        if (has_in) { v.x=o[4*i+0]; v.y=o[4*i+1]; v.z=o[4*i+2]; v.w=o[4*i+3]; }
        else        { v.x=accA[4*i+0]; v.y=accA[4*i+1]; v.z=accA[4*i+2]; v.w=accA[4*i+3]; }
        po[i] = v;
    }
}

extern "C" void kernel_launch(void* const* d_in, const int* in_sizes, int n_in,
                              void* d_out, int out_size, void* d_ws, size_t ws_size,
                              hipStream_t stream) {
    const float* nf      = (const float*)d_in[0];
    const int*   src_out = (const int*)d_in[1];
    const int*   dst_out = (const int*)d_in[2];
    const float* nef_out = (const float*)d_in[3];
    const int*   src_in  = (const int*)d_in[4];
    const int*   dst_in  = (const int*)d_in[5];
    const float* nef_in  = (const float*)d_in[6];
    const float* w_o2i1  = (const float*)d_in[7];
    const float* b_o2i1  = (const float*)d_in[8];
    const float* w_o2i2  = (const float*)d_in[9];
    const float* b_o2i2  = (const float*)d_in[10];
    const float* w_i2o1  = (const float*)d_in[11];
    const float* b_i2o1  = (const float*)d_in[12];
    const float* w_i2o2  = (const float*)d_in[13];
    const float* b_i2o2  = (const float*)d_in[14];
    const float* w_red1  = (const float*)d_in[15];
    const float* b_red1  = (const float*)d_in[16];
    const float* w_red2  = (const float*)d_in[17];
    const float* b_red2  = (const float*)d_in[18];

    int n_nodes = in_sizes[0] / IN_NF;
    int n_edges = in_sizes[1];
    float* out = (float*)d_out;

    dim3 blk(256);
    dim3 egrid((n_edges + 255) / 256);
    dim3 hgrid((n_edges / 4 + 256) / 256 + 1);
    dim3 ngrid(((size_t)n_nodes * NT + 255) / 256);
    dim3 sgrid(2 * SCAN_NB);

    size_t off_bytes = (size_t)2 * n_nodes * sizeof(int);
    size_t nf16_bytes = (size_t)n_nodes * 16 * sizeof(unsigned short);
    size_t msg_bytes = (size_t)n_edges * 16 * sizeof(unsigned short);
    size_t need_fast = off_bytes + nf16_bytes + 2 * msg_bytes + 256;

    if (ws_size >= need_fast) {
        int* curA = (int*)d_ws;
        int* curB = curA + n_nodes;
        unsigned short* nf16 = (unsigned short*)(curB + n_nodes);
        unsigned short* msgA = nf16 + (size_t)n_nodes * 16;
        unsigned short* msgB = msgA + (size_t)n_edges * 16;
        // block-sum scratch aliases into msgA (dead until k_edges runs)
        int* bsum = (int*)msgA;

        int nb_conv = (n_nodes + 255) / 256;
        int nb_hist = (n_edges / 4 + 256) / 256 + 1;
        dim3 pgrid(nb_conv + nb_hist);

        int nbe = (n_edges + 255) / 256;
        dim3 edge_grid(2 * nbe);

        hipMemsetAsync(d_ws, 0, off_bytes, stream);
        k_pre<<<pgrid, blk, 0, stream>>>(nf, nf16, n_nodes, dst_out, dst_in,
                                         curA, curB, n_edges, nb_conv);
        k_scan_partial<<<sgrid, blk, 0, stream>>>(curA, curB, n_nodes, bsum);
        k_scan_bsum<<<dim3(1), dim3(64), 0, stream>>>(bsum);
        k_scan_final<<<sgrid, blk, 0, stream>>>(curA, curB, n_nodes, bsum);
        k_edges<<<edge_grid, blk, 0, stream>>>(nf16,
                                               src_out, dst_out, nef_out,
                                               src_in, dst_in, nef_in,
                                               w_o2i1, b_o2i1, w_o2i2, b_o2i2,
                                               w_i2o1, b_i2o1, w_i2o2, b_i2o2,
                                               curA, curB, msgA, msgB,
                                               n_edges, nbe);
        k_gather<<<ngrid, blk, 0, stream>>>(curA, curB, msgA, msgB,
                                            w_red1, b_red1, w_red2, b_red2,
                                            out, n_nodes);
    } else {
        int* off_out  = (int*)d_ws;
        int* off_in   = off_out + n_nodes;
        int* perm_out = off_in + n_nodes;
        int* perm_in  = perm_out + n_edges;
        int* bsum = perm_out;  // dead until k_scatter

        hipMemsetAsync(d_ws, 0, off_bytes, stream);
        k_hist<<<hgrid, blk, 0, stream>>>(dst_out, dst_in, off_out, off_in, n_edges);
        k_scan_partial<<<sgrid, blk, 0, stream>>>(off_out, off_in, n_nodes, bsum);
        k_scan_bsum<<<dim3(1), dim3(64), 0, stream>>>(bsum);
        k_scan_final<<<sgrid, blk, 0, stream>>>(off_out, off_in, n_nodes, bsum);
        k_scatter<<<egrid, blk, 0, stream>>>(dst_out, dst_in, off_out, off_in,
                                             perm_out, perm_in, n_edges);
        k_node_fused<<<ngrid, blk, 0, stream>>>(nf, src_out, nef_out, src_in, nef_in,
                                          off_out, off_in, perm_out, perm_in,
                                          w_o2i1, b_o2i1, w_o2i2, b_o2i2,
                                          w_i2o1, b_i2o1, w_i2o2, b_i2o2,
                                          w_red1, b_red1, w_red2, b_red2,
                                          out, n_nodes);
    }
}